// Round 1
// baseline (849.028 us; speedup 1.0000x reference)
//
#include <hip/hip_runtime.h>

#define QLEN 256
#define DDIM 64
#define WOUT 32

typedef __bf16 b8v __attribute__((ext_vector_type(8)));
typedef float f4v __attribute__((ext_vector_type(4)));

__device__ __forceinline__ f4v MFMA(b8v a, b8v b, f4v c) {
  return __builtin_amdgcn_mfma_f32_16x16x32_bf16(a, b, c, 0, 0, 0);
}

__device__ __forceinline__ float sigmoidf_(float x) {
  return 1.0f / (1.0f + __expf(-x));
}

// ---------------- Kernel 1: Kalman scan (256 steps) ----------------
// 256 WGs x 512 threads; each WG owns 8 batch rows. M-tile=16 (rows 8..15 zero).
__global__ __launch_bounds__(512, 2)
void k_kalman(const float* __restrict__ x_in,
              const float* __restrict__ conv_w, const float* __restrict__ conv_b,
              const float* __restrict__ fc1_w,  const float* __restrict__ fc1_b,
              const float* __restrict__ fc2_w,  const float* __restrict__ fc2_b,
              const float* __restrict__ rot1_w, const float* __restrict__ rot1_b,
              const float* __restrict__ rot2_w, const float* __restrict__ rot2_b,
              float* __restrict__ out)
{
  __shared__ __bf16 SM[24704];
  __shared__ float  CS[16];
  const int tid = threadIdx.x;
  const int w  = tid >> 6;      // wave 0..7
  const int l  = tid & 63;
  const int lr = l & 15;
  const int lg = l >> 4;
  const int wg = blockIdx.x;

  __bf16* XP   = SM;            // [16][72]  x_post bf16
  __bf16* T1   = SM + 1152;     // [16][136] relu(rot1)
  __bf16* TC   = SM + 3328;     // [16][136] relu(conv)
  __bf16* T2   = SM + 5504;     // [16][136] relu(fc1)
  __bf16* XPRI = SM + 7680;     // [8][64]
  __bf16* INV  = SM + 8192;     // [8][64]
  __bf16* FEAT = SM + 8704;     // [5][16][200] feat ring

  for (int i = tid; i < 24704; i += 512) SM[i] = (__bf16)0.0f;

  // ---- register-resident B fragments (weights, bf16) ----
  const int hcol = 16*w + lr;
  b8v fr1[2], ff1[4], fcv[30], ff2[4], wr2[4];
  #pragma unroll
  for (int q = 0; q < 2; ++q)
    #pragma unroll
    for (int j = 0; j < 8; ++j)
      fr1[q][j] = (__bf16)rot1_w[hcol*64 + q*32 + lg*8 + j];
  #pragma unroll
  for (int q = 0; q < 4; ++q)
    #pragma unroll
    for (int j = 0; j < 8; ++j)
      ff1[q][j] = (__bf16)fc1_w[hcol*128 + q*32 + lg*8 + j];
  #pragma unroll
  for (int L = 0; L < 5; ++L)
    #pragma unroll
    for (int q = 0; q < 6; ++q)
      #pragma unroll
      for (int j = 0; j < 8; ++j)
        fcv[L*6+q][j] = (__bf16)conv_w[(hcol*192 + q*32 + lg*8 + j)*5 + (4-L)];
  {
    const int h2 = (w < 4) ? hcol : 0;   // fc2_w has only 64 rows
    #pragma unroll
    for (int q = 0; q < 4; ++q)
      #pragma unroll
      for (int j = 0; j < 8; ++j)
        ff2[q][j] = (__bf16)fc2_w[h2*128 + q*32 + lg*8 + j];
  }
  const int e2 = l >> 3, j2 = l & 7;     // rot2 layout (used by wave 7)
  #pragma unroll
  for (int o = 0; o < 2; ++o)
    #pragma unroll
    for (int hf = 0; hf < 2; ++hf)
      #pragma unroll
      for (int j = 0; j < 8; ++j)
        wr2[o*2+hf][j] = (__bf16)rot2_w[o*128 + j2*16 + hf*8 + j];

  const float b_r1 = rot1_b[hcol];
  const float b_cv = conv_b[hcol];
  const float b_f1 = fc1_b[hcol];
  const float b_f2 = fc2_b[(w < 4) ? hcol : 0];
  const float rb0 = rot2_b[0], rb1 = rot2_b[1];
  const float PI_F = 3.14159274f;

  __syncthreads();

  for (int t = 0; t < QLEN; ++t) {
    // P1: t1 = relu(x_post @ rot1_w^T + b)
    {
      b8v a0 = *(const b8v*)&XP[lr*72      + lg*8];
      b8v a1 = *(const b8v*)&XP[lr*72 + 32 + lg*8];
      f4v C = {};
      C = MFMA(a0, fr1[0], C);
      C = MFMA(a1, fr1[1], C);
      #pragma unroll
      for (int r = 0; r < 4; ++r) {
        float v = C[r] + b_r1; v = v > 0.f ? v : 0.f;
        T1[(lg*4+r)*136 + hcol] = (__bf16)v;
      }
    }
    __syncthreads();

    // P2: rp = t1 @ rot2_w^T + b -> rho,phi -> c,s   (wave 7 only)
    if (w == 7) {
      float acc0 = 0.f, acc1 = 0.f;
      #pragma unroll
      for (int hf = 0; hf < 2; ++hf) {
        b8v x = *(const b8v*)&T1[e2*136 + j2*16 + hf*8];
        #pragma unroll
        for (int j = 0; j < 8; ++j) {
          float xv = (float)x[j];
          acc0 += xv * (float)wr2[0*2+hf][j];
          acc1 += xv * (float)wr2[1*2+hf][j];
        }
      }
      #pragma unroll
      for (int m = 1; m < 8; m <<= 1) {
        acc0 += __shfl_xor(acc0, m, 64);
        acc1 += __shfl_xor(acc1, m, 64);
      }
      if (j2 == 0) {
        float rho = 1.5f * sigmoidf_(acc0 + rb0);
        float phi = PI_F * tanhf(acc1 + rb1);
        CS[e2*2+0] = rho * __cosf(phi);
        CS[e2*2+1] = rho * __sinf(phi);
      }
    }
    __syncthreads();

    // P3: rotation, innov, diff, feat write (thread = (e=w, d=l))
    {
      const int e = w, d = l;
      float cc = CS[e*2+0], ss = CS[e*2+1];
      float lo  = (float)XP[e*72 + (d & 31)];
      float hi  = (float)XP[e*72 + (d & 31) + 32];
      float xpv = (float)XP[e*72 + d];
      float xpri = (d < 32) ? (lo*cc - hi*ss) : (lo*ss + hi*cc);
      const long base = ((long)(wg*8 + e)*QLEN + t)*DDIM + d;
      float yt = x_in[base];
      float yp = (t > 0) ? x_in[base - DDIM] : yt;
      float innov = yt - xpri;
      float diff  = yt - yp;
      __bf16* fr = FEAT + (t % 5)*3200 + e*200;
      fr[d]       = (__bf16)innov;
      fr[64 + d]  = (__bf16)xpv;
      fr[128 + d] = (__bf16)diff;
      XPRI[e*64 + d] = (__bf16)xpri;
      INV [e*64 + d] = (__bf16)innov;
    }
    __syncthreads();

    // P4: conv over feat ring (K = 5 lags x 192)
    {
      f4v C0 = {}, C1 = {};
      #pragma unroll
      for (int L = 0; L < 5; ++L) {
        const __bf16* fb = FEAT + ((t - L + 5) % 5)*3200;
        #pragma unroll
        for (int q = 0; q < 6; ++q) {
          b8v a = *(const b8v*)&fb[lr*200 + q*32 + lg*8];
          if (((L*6+q) & 1) == 0) C0 = MFMA(a, fcv[L*6+q], C0);
          else                    C1 = MFMA(a, fcv[L*6+q], C1);
        }
      }
      #pragma unroll
      for (int r = 0; r < 4; ++r) {
        float v = C0[r] + C1[r] + b_cv; v = v > 0.f ? v : 0.f;
        TC[(lg*4+r)*136 + hcol] = (__bf16)v;
      }
    }
    __syncthreads();

    // P5: fc1
    {
      f4v C0 = {}, C1 = {};
      #pragma unroll
      for (int q = 0; q < 4; ++q) {
        b8v a = *(const b8v*)&TC[lr*136 + q*32 + lg*8];
        if (q & 1) C1 = MFMA(a, ff1[q], C1); else C0 = MFMA(a, ff1[q], C0);
      }
      #pragma unroll
      for (int r = 0; r < 4; ++r) {
        float v = C0[r] + C1[r] + b_f1; v = v > 0.f ? v : 0.f;
        T2[(lg*4+r)*136 + hcol] = (__bf16)v;
      }
    }
    __syncthreads();

    // P6: K = sigmoid(fc2), x_post = x_pri + K*innov   (waves 0..3)
    if (w < 4) {
      f4v C0 = {}, C1 = {};
      #pragma unroll
      for (int q = 0; q < 4; ++q) {
        b8v a = *(const b8v*)&T2[lr*136 + q*32 + lg*8];
        if (q & 1) C1 = MFMA(a, ff2[q], C1); else C0 = MFMA(a, ff2[q], C0);
      }
      if (lg < 2) {
        #pragma unroll
        for (int r = 0; r < 4; ++r) {
          int e = lg*4 + r;
          float K = sigmoidf_(C0[r] + C1[r] + b_f2);
          float xn = (float)XPRI[e*64 + hcol] + K * (float)INV[e*64 + hcol];
          XP[e*72 + hcol] = (__bf16)xn;
        }
      }
    }
    __syncthreads();
  }

  // stash x_post into out[b][0][:] (GRU kernel reads then overwrites)
  {
    const int e = w, d = l;
    out[((long)(wg*8 + e)*WOUT)*DDIM + d] = (float)XP[e*72 + d];
  }
}

// ---------------- Kernel 2: GRU head (32 steps) ----------------
// 64 WGs x 512 threads; each WG owns 32 batch rows (2 M-tiles, no padding).
__global__ __launch_bounds__(512, 2)
void k_gru(const float* __restrict__ gru_wih, const float* __restrict__ gru_whh,
           const float* __restrict__ gru_bih, const float* __restrict__ gru_bhh,
           const float* __restrict__ out_w,   const float* __restrict__ out_b,
           float* __restrict__ out)
{
  __shared__ __bf16 CUR[32*72];
  __shared__ __bf16 HB [32*136];
  const int tid = threadIdx.x;
  const int w  = tid >> 6, l = tid & 63, lr = l & 15, lg = l >> 4;
  const int g = blockIdx.x;

  for (int i = tid; i < 32*136; i += 512) HB[i] = (__bf16)0.f;
  for (int i = tid; i < 32*64; i += 512) {
    int e = i >> 6, d = i & 63;
    CUR[e*72 + d] = (__bf16)out[((long)(g*32 + e)*WOUT)*DDIM + d];
  }

  // B-fragments: wave w owns gate-col tiles n = w, w+8, w+16
  b8v fih[3][2], fhh[3][4], fo[4];
  #pragma unroll
  for (int n3 = 0; n3 < 3; ++n3) {
    int row = 16*(w + 8*n3) + lr;
    #pragma unroll
    for (int q = 0; q < 2; ++q)
      #pragma unroll
      for (int j = 0; j < 8; ++j)
        fih[n3][q][j] = (__bf16)gru_wih[row*64 + q*32 + lg*8 + j];
    #pragma unroll
    for (int q = 0; q < 4; ++q)
      #pragma unroll
      for (int j = 0; j < 8; ++j)
        fhh[n3][q][j] = (__bf16)gru_whh[row*128 + q*32 + lg*8 + j];
  }
  {
    int row = 16*(w & 3) + lr;
    #pragma unroll
    for (int q = 0; q < 4; ++q)
      #pragma unroll
      for (int j = 0; j < 8; ++j)
        fo[q][j] = (__bf16)out_w[row*128 + q*32 + lg*8 + j];
  }
  const int jh = 16*w + lr;
  const float b_ir = gru_bih[jh], b_iz = gru_bih[128+jh], b_in = gru_bih[256+jh];
  const float b_hr = gru_bhh[jh], b_hz = gru_bhh[128+jh], b_hn = gru_bhh[256+jh];
  const float b_o  = out_b[16*(w & 3) + lr];
  __syncthreads();

  for (int s = 0; s < WOUT; ++s) {
    f4v cI[2][3] = {}, cH[2][3] = {};
    #pragma unroll
    for (int mt = 0; mt < 2; ++mt) {
      #pragma unroll
      for (int q = 0; q < 2; ++q) {
        b8v a = *(const b8v*)&CUR[(mt*16+lr)*72 + q*32 + lg*8];
        #pragma unroll
        for (int n3 = 0; n3 < 3; ++n3) cI[mt][n3] = MFMA(a, fih[n3][q], cI[mt][n3]);
      }
      #pragma unroll
      for (int q = 0; q < 4; ++q) {
        b8v a = *(const b8v*)&HB[(mt*16+lr)*136 + q*32 + lg*8];
        #pragma unroll
        for (int n3 = 0; n3 < 3; ++n3) cH[mt][n3] = MFMA(a, fhh[n3][q], cH[mt][n3]);
      }
    }
    __syncthreads();   // all HB reads done before gate writes

    #pragma unroll
    for (int mt = 0; mt < 2; ++mt)
      #pragma unroll
      for (int r = 0; r < 4; ++r) {
        int e = mt*16 + lg*4 + r;
        float ir = cI[mt][0][r] + b_ir, iz = cI[mt][1][r] + b_iz, in_ = cI[mt][2][r] + b_in;
        float hr = cH[mt][0][r] + b_hr, hz = cH[mt][1][r] + b_hz, hn  = cH[mt][2][r] + b_hn;
        float rr = sigmoidf_(ir + hr);
        float zz = sigmoidf_(iz + hz);
        float nn = tanhf(in_ + rr*hn);
        float hold = (float)HB[e*136 + jh];
        float hnew = (1.f - zz)*nn + zz*hold;
        HB[e*136 + jh] = (__bf16)hnew;
      }
    __syncthreads();   // h_new complete

    // out projection: wave w -> (mt = w>>2, dcol tile = w&3)
    {
      int mt = w >> 2, dcol = 16*(w & 3) + lr;
      f4v C0 = {};
      #pragma unroll
      for (int q = 0; q < 4; ++q) {
        b8v a = *(const b8v*)&HB[(mt*16+lr)*136 + q*32 + lg*8];
        C0 = MFMA(a, fo[q], C0);
      }
      #pragma unroll
      for (int r = 0; r < 4; ++r) {
        int e = mt*16 + lg*4 + r;
        float cn = (float)CUR[e*72 + dcol] + C0[r] + b_o;
        CUR[e*72 + dcol] = (__bf16)cn;
        out[(((long)(g*32 + e))*WOUT + s)*DDIM + dcol] = cn;
      }
    }
    __syncthreads();
  }
}

extern "C" void kernel_launch(void* const* d_in, const int* in_sizes, int n_in,
                              void* d_out, int out_size, void* d_ws, size_t ws_size,
                              hipStream_t stream) {
  (void)in_sizes; (void)n_in; (void)d_ws; (void)ws_size; (void)out_size;
  const float* x_in   = (const float*)d_in[0];
  // d_in[1] = w_out (scalar 32), hardcoded
  const float* conv_w = (const float*)d_in[2];
  const float* conv_b = (const float*)d_in[3];
  const float* fc1_w  = (const float*)d_in[4];
  const float* fc1_b  = (const float*)d_in[5];
  const float* fc2_w  = (const float*)d_in[6];
  const float* fc2_b  = (const float*)d_in[7];
  const float* rot1_w = (const float*)d_in[8];
  const float* rot1_b = (const float*)d_in[9];
  const float* rot2_w = (const float*)d_in[10];
  const float* rot2_b = (const float*)d_in[11];
  const float* gwih   = (const float*)d_in[12];
  const float* gwhh   = (const float*)d_in[13];
  const float* gbih   = (const float*)d_in[14];
  const float* gbhh   = (const float*)d_in[15];
  const float* ow     = (const float*)d_in[16];
  const float* ob     = (const float*)d_in[17];
  float* out = (float*)d_out;

  k_kalman<<<256, 512, 0, stream>>>(x_in, conv_w, conv_b, fc1_w, fc1_b,
                                    fc2_w, fc2_b, rot1_w, rot1_b,
                                    rot2_w, rot2_b, out);
  k_gru<<<64, 512, 0, stream>>>(gwih, gwhh, gbih, gbhh, ow, ob, out);
}

// Round 2
// 673.018 us; speedup vs baseline: 1.2615x; 1.2615x over previous
//
#include <hip/hip_runtime.h>

#define QLEN 256
#define DDIM 64
#define WOUT 32

typedef __bf16 b8v __attribute__((ext_vector_type(8)));
typedef float f4v __attribute__((ext_vector_type(4)));

__device__ __forceinline__ f4v MFMA(b8v a, b8v b, f4v c) {
  return __builtin_amdgcn_mfma_f32_16x16x32_bf16(a, b, c, 0, 0, 0);
}
__device__ __forceinline__ float sigmoidf_(float x) { return 1.0f/(1.0f+__expf(-x)); }
__device__ __forceinline__ float tanhf_(float x)    { return 1.0f - 2.0f/(__expf(2.0f*x)+1.0f); }

// ---------------- Kernel 1: Kalman scan (256 steps) ----------------
// 256 WGs x 512 threads (8 waves); each WG owns 8 batch rows (M=16 tile, rows 8..15 zero).
// Conv K-split: waves w and w+4 pair up; each reads A-frags once for 2 N-tiles.
__global__ __launch_bounds__(512, 2)
void k_kalman(const float* __restrict__ x_in,
              const float* __restrict__ conv_w, const float* __restrict__ conv_b,
              const float* __restrict__ fc1_w,  const float* __restrict__ fc1_b,
              const float* __restrict__ fc2_w,  const float* __restrict__ fc2_b,
              const float* __restrict__ rot1_w, const float* __restrict__ rot1_b,
              const float* __restrict__ rot2_w, const float* __restrict__ rot2_b,
              float* __restrict__ out)
{
  __shared__ __align__(16) __bf16 SMB[23680];
  __shared__ __align__(16) float  SMF[3584];
  const int tid = threadIdx.x;
  const int w  = tid >> 6;      // wave 0..7
  const int l  = tid & 63;
  const int lr = l & 15;
  const int lg = l >> 4;
  const int wg = blockIdx.x;

  __bf16* XPB  = SMB;            // [16][72]  x_post bf16 shadow (A-operand)
  __bf16* T1   = SMB + 1152;     // [16][136] relu(rot1)
  __bf16* TC   = SMB + 3328;     // [16][136] relu(conv)
  __bf16* T2   = SMB + 5504;     // [16][136] relu(fc1)
  __bf16* FEAT = SMB + 7680;     // [5][16][200] feat ring
  float*  XPF  = SMF;            // [8][64] x_post fp32 (master state)
  float*  XPRI = SMF + 512;      // [8][64]
  float*  INV  = SMF + 1024;     // [8][64]
  float*  PART = SMF + 1536;     // [128][16] conv partial sums (col-major tiles)

  for (int i = tid; i < 23680; i += 512) SMB[i] = (__bf16)0.0f;
  for (int i = tid; i < 3584;  i += 512) SMF[i] = 0.0f;

  const int hcol = 16*w + lr;
  const int tlo  = 2*(w & 3);          // this pair's N-tile base (tiles tlo, tlo+1)
  const int qb   = (w < 4) ? 0 : 3;    // K-subset: q in {qb..qb+2} per lag

  // ---- register-resident B fragments (weights, bf16) ----
  b8v r1B[2], f1B[4], f2B[4], cvB[15][2];
  #pragma unroll
  for (int q = 0; q < 2; ++q)
    #pragma unroll
    for (int j = 0; j < 8; ++j)
      r1B[q][j] = (__bf16)rot1_w[hcol*64 + q*32 + lg*8 + j];
  #pragma unroll
  for (int q = 0; q < 4; ++q)
    #pragma unroll
    for (int j = 0; j < 8; ++j)
      f1B[q][j] = (__bf16)fc1_w[hcol*128 + q*32 + lg*8 + j];
  {
    const int h2 = (w < 4) ? hcol : 0;   // fc2_w has 64 rows
    #pragma unroll
    for (int q = 0; q < 4; ++q)
      #pragma unroll
      for (int j = 0; j < 8; ++j)
        f2B[q][j] = (__bf16)fc2_w[h2*128 + q*32 + lg*8 + j];
  }
  #pragma unroll
  for (int L = 0; L < 5; ++L)
    #pragma unroll
    for (int qi = 0; qi < 3; ++qi)
      #pragma unroll
      for (int ti = 0; ti < 2; ++ti)
        #pragma unroll
        for (int j = 0; j < 8; ++j)
          cvB[L*3+qi][ti][j] =
            (__bf16)conv_w[((tlo+ti)*16 + lr)*960 + ((qb+qi)*32 + lg*8 + j)*5 + (4-L)];

  const float b_r1 = rot1_b[hcol];
  const float b_f1 = fc1_b[hcol];
  const float b_f2 = fc2_b[(w < 4) ? hcol : 0];
  const float bc0  = conv_b[tlo*16 + lr];
  const float bc1  = conv_b[(tlo+1)*16 + lr];
  const float r2w00 = rot2_w[l],       r2w01 = rot2_w[64 + l];
  const float r2w10 = rot2_w[128 + l], r2w11 = rot2_w[192 + l];
  const float rb0 = rot2_b[0], rb1 = rot2_b[1];
  const float PI_F = 3.14159274f;

  const float* xptr = x_in + ((long)(wg*8 + w)*QLEN)*DDIM + l;
  float y_cur = xptr[0];
  float y_prv = y_cur;
  int slot = 0;

  __syncthreads();

  for (int t = 0; t < QLEN; ++t) {
    // P1: t1 = relu(x_post @ rot1_w^T + b)
    {
      b8v a0 = *(const b8v*)&XPB[lr*72      + lg*8];
      b8v a1 = *(const b8v*)&XPB[lr*72 + 32 + lg*8];
      f4v C = {};
      C = MFMA(a0, r1B[0], C);
      C = MFMA(a1, r1B[1], C);
      #pragma unroll
      for (int r = 0; r < 4; ++r) {
        float v = C[r] + b_r1; v = v > 0.f ? v : 0.f;
        T1[(lg*4+r)*136 + hcol] = (__bf16)v;
      }
    }
    __syncthreads();   // B1

    // P2'+P3: wave w owns element e=w: in-wave rot2 -> rotation -> feat
    float y_nxt;
    {
      float t1a = (float)T1[w*136 + l];
      float t1b = (float)T1[w*136 + 64 + l];
      float acc0 = t1a*r2w00 + t1b*r2w01;
      float acc1 = t1a*r2w10 + t1b*r2w11;
      #pragma unroll
      for (int m = 1; m < 64; m <<= 1) {
        acc0 += __shfl_xor(acc0, m, 64);
        acc1 += __shfl_xor(acc1, m, 64);
      }
      float rho = 1.5f * sigmoidf_(acc0 + rb0);
      float phi = PI_F * tanhf_(acc1 + rb1);
      float cc = rho * __cosf(phi);
      float ss = rho * __sinf(phi);
      float xpv = XPF[w*64 + l];
      float lo  = XPF[w*64 + (l & 31)];
      float hi  = XPF[w*64 + (l & 31) + 32];
      float xpri = (l < 32) ? (lo*cc - hi*ss) : (lo*ss + hi*cc);
      float innov = y_cur - xpri;
      float diff  = y_cur - y_prv;
      __bf16* fr = FEAT + slot*3200 + w*200;
      fr[l]       = (__bf16)innov;
      fr[64 + l]  = (__bf16)xpv;
      fr[128 + l] = (__bf16)diff;
      XPRI[w*64 + l] = xpri;
      INV [w*64 + l] = innov;
      // prefetch next y (one full step of latency cover)
      y_nxt = (t+1 < QLEN) ? xptr[(t+1)*DDIM] : y_cur;
    }
    __syncthreads();   // B2

    // P4: conv half-K, 2 N-tiles per wave
    f4v C0 = {}, C1 = {};
    {
      #pragma unroll
      for (int L = 0; L < 5; ++L) {
        int s5 = slot - L; s5 = (s5 < 0) ? s5 + 5 : s5;
        const __bf16* fb = FEAT + s5*3200 + lr*200 + qb*32 + lg*8;
        #pragma unroll
        for (int qi = 0; qi < 3; ++qi) {
          b8v a = *(const b8v*)&fb[qi*32];
          C0 = MFMA(a, cvB[L*3+qi][0], C0);
          C1 = MFMA(a, cvB[L*3+qi][1], C1);
        }
      }
      if (w >= 4) {
        *(f4v*)&PART[(tlo*16 + lr)*16 + 4*lg]     = C0;
        *(f4v*)&PART[((tlo+1)*16 + lr)*16 + 4*lg] = C1;
      }
    }
    __syncthreads();   // B3

    // P4b: combine halves + relu + TC write (waves 0..3)
    if (w < 4) {
      f4v p0 = *(const f4v*)&PART[(tlo*16 + lr)*16 + 4*lg];
      f4v p1 = *(const f4v*)&PART[((tlo+1)*16 + lr)*16 + 4*lg];
      #pragma unroll
      for (int r = 0; r < 4; ++r) {
        float v0 = C0[r] + p0[r] + bc0; v0 = v0 > 0.f ? v0 : 0.f;
        float v1 = C1[r] + p1[r] + bc1; v1 = v1 > 0.f ? v1 : 0.f;
        TC[(lg*4+r)*136 + tlo*16 + lr]     = (__bf16)v0;
        TC[(lg*4+r)*136 + (tlo+1)*16 + lr] = (__bf16)v1;
      }
    }
    __syncthreads();   // B4

    // P5: fc1
    {
      f4v D0 = {}, D1 = {};
      #pragma unroll
      for (int q = 0; q < 4; ++q) {
        b8v a = *(const b8v*)&TC[lr*136 + q*32 + lg*8];
        if (q & 1) D1 = MFMA(a, f1B[q], D1); else D0 = MFMA(a, f1B[q], D0);
      }
      #pragma unroll
      for (int r = 0; r < 4; ++r) {
        float v = D0[r] + D1[r] + b_f1; v = v > 0.f ? v : 0.f;
        T2[(lg*4+r)*136 + hcol] = (__bf16)v;
      }
    }
    __syncthreads();   // B5

    // P6: K = sigmoid(fc2), x_post = x_pri + K*innov (waves 0..3, fp32 state)
    if (w < 4) {
      f4v D0 = {}, D1 = {};
      #pragma unroll
      for (int q = 0; q < 4; ++q) {
        b8v a = *(const b8v*)&T2[lr*136 + q*32 + lg*8];
        if (q & 1) D1 = MFMA(a, f2B[q], D1); else D0 = MFMA(a, f2B[q], D0);
      }
      if (lg < 2) {
        #pragma unroll
        for (int r = 0; r < 4; ++r) {
          int e = lg*4 + r;
          float K = sigmoidf_(D0[r] + D1[r] + b_f2);
          float xn = XPRI[e*64 + hcol] + K * INV[e*64 + hcol];
          XPF[e*64 + hcol] = xn;
          XPB[e*72 + hcol] = (__bf16)xn;
        }
      }
    }
    __syncthreads();   // B6

    y_prv = y_cur; y_cur = y_nxt;
    slot = (slot == 4) ? 0 : slot + 1;
  }

  // stash fp32 x_post into out[b][0][:] (GRU kernel reads then overwrites)
  out[((long)(wg*8 + w)*WOUT)*DDIM + l] = XPF[w*64 + l];
}

// ---------------- Kernel 2: GRU head (32 steps) ----------------
// 128 WGs x 512 threads; each WG owns 16 batch rows (1 M-tile, no padding).
__global__ __launch_bounds__(512, 2)
void k_gru(const float* __restrict__ gru_wih, const float* __restrict__ gru_whh,
           const float* __restrict__ gru_bih, const float* __restrict__ gru_bhh,
           const float* __restrict__ out_w,   const float* __restrict__ out_b,
           float* __restrict__ out)
{
  __shared__ __align__(16) __bf16 CUR[16*72];
  __shared__ __align__(16) __bf16 HB [16*136];
  const int tid = threadIdx.x;
  const int w  = tid >> 6, l = tid & 63, lr = l & 15, lg = l >> 4;
  const int g = blockIdx.x;

  for (int i = tid; i < 16*136; i += 512) HB[i] = (__bf16)0.f;
  for (int i = tid; i < 16*64; i += 512) {
    int e = i >> 6, d = i & 63;
    CUR[e*72 + d] = (__bf16)out[((long)(g*16 + e)*WOUT)*DDIM + d];
  }

  // B-fragments: wave w owns gate-col tiles n = w, w+8, w+16
  b8v fih[3][2], fhh[3][4], fo[4];
  #pragma unroll
  for (int n3 = 0; n3 < 3; ++n3) {
    int row = 16*(w + 8*n3) + lr;
    #pragma unroll
    for (int q = 0; q < 2; ++q)
      #pragma unroll
      for (int j = 0; j < 8; ++j)
        fih[n3][q][j] = (__bf16)gru_wih[row*64 + q*32 + lg*8 + j];
    #pragma unroll
    for (int q = 0; q < 4; ++q)
      #pragma unroll
      for (int j = 0; j < 8; ++j)
        fhh[n3][q][j] = (__bf16)gru_whh[row*128 + q*32 + lg*8 + j];
  }
  {
    int row = 16*(w & 3) + lr;
    #pragma unroll
    for (int q = 0; q < 4; ++q)
      #pragma unroll
      for (int j = 0; j < 8; ++j)
        fo[q][j] = (__bf16)out_w[row*128 + q*32 + lg*8 + j];
  }
  const int jh = 16*w + lr;
  const float b_ir = gru_bih[jh], b_iz = gru_bih[128+jh], b_in = gru_bih[256+jh];
  const float b_hr = gru_bhh[jh], b_hz = gru_bhh[128+jh], b_hn = gru_bhh[256+jh];
  const float b_o  = out_b[16*(w & 3) + lr];
  const int dcol = 16*(w & 3) + lr;
  __syncthreads();

  for (int s = 0; s < WOUT; ++s) {
    f4v cI[3] = {}, cH[3] = {};
    #pragma unroll
    for (int q = 0; q < 2; ++q) {
      b8v a = *(const b8v*)&CUR[lr*72 + q*32 + lg*8];
      #pragma unroll
      for (int n3 = 0; n3 < 3; ++n3) cI[n3] = MFMA(a, fih[n3][q], cI[n3]);
    }
    #pragma unroll
    for (int q = 0; q < 4; ++q) {
      b8v a = *(const b8v*)&HB[lr*136 + q*32 + lg*8];
      #pragma unroll
      for (int n3 = 0; n3 < 3; ++n3) cH[n3] = MFMA(a, fhh[n3][q], cH[n3]);
    }
    __syncthreads();   // all CUR/HB reads done before writes

    #pragma unroll
    for (int r = 0; r < 4; ++r) {
      int e = lg*4 + r;
      float ir = cI[0][r] + b_ir, iz = cI[1][r] + b_iz, in_ = cI[2][r] + b_in;
      float hr = cH[0][r] + b_hr, hz = cH[1][r] + b_hz, hn  = cH[2][r] + b_hn;
      float rr = sigmoidf_(ir + hr);
      float zz = sigmoidf_(iz + hz);
      float nn = tanhf_(in_ + rr*hn);
      float hold = (float)HB[e*136 + jh];
      float hnew = (1.f - zz)*nn + zz*hold;
      HB[e*136 + jh] = (__bf16)hnew;
    }
    __syncthreads();   // h_new complete

    if (w < 4) {
      f4v C0 = {};
      #pragma unroll
      for (int q = 0; q < 4; ++q) {
        b8v a = *(const b8v*)&HB[lr*136 + q*32 + lg*8];
        C0 = MFMA(a, fo[q], C0);
      }
      #pragma unroll
      for (int r = 0; r < 4; ++r) {
        int e = lg*4 + r;
        float cn = (float)CUR[e*72 + dcol] + C0[r] + b_o;
        CUR[e*72 + dcol] = (__bf16)cn;
        out[(((long)(g*16 + e))*WOUT + s)*DDIM + dcol] = cn;
      }
    }
    __syncthreads();
  }
}

extern "C" void kernel_launch(void* const* d_in, const int* in_sizes, int n_in,
                              void* d_out, int out_size, void* d_ws, size_t ws_size,
                              hipStream_t stream) {
  (void)in_sizes; (void)n_in; (void)d_ws; (void)ws_size; (void)out_size;
  const float* x_in   = (const float*)d_in[0];
  const float* conv_w = (const float*)d_in[2];
  const float* conv_b = (const float*)d_in[3];
  const float* fc1_w  = (const float*)d_in[4];
  const float* fc1_b  = (const float*)d_in[5];
  const float* fc2_w  = (const float*)d_in[6];
  const float* fc2_b  = (const float*)d_in[7];
  const float* rot1_w = (const float*)d_in[8];
  const float* rot1_b = (const float*)d_in[9];
  const float* rot2_w = (const float*)d_in[10];
  const float* rot2_b = (const float*)d_in[11];
  const float* gwih   = (const float*)d_in[12];
  const float* gwhh   = (const float*)d_in[13];
  const float* gbih   = (const float*)d_in[14];
  const float* gbhh   = (const float*)d_in[15];
  const float* ow     = (const float*)d_in[16];
  const float* ob     = (const float*)d_in[17];
  float* out = (float*)d_out;

  k_kalman<<<256, 512, 0, stream>>>(x_in, conv_w, conv_b, fc1_w, fc1_b,
                                    fc2_w, fc2_b, rot1_w, rot1_b,
                                    rot2_w, rot2_b, out);
  k_gru<<<128, 512, 0, stream>>>(gwih, gwhh, gbih, gbhh, ow, ob, out);
}